// Round 10
// baseline (1409.484 us; speedup 1.0000x reference)
//
#include <hip/hip_runtime.h>

// NetG: seq2seq GRU (enc GRU -> +noise -> dec GRU -> FC head)
// B=512, T=256, H=256, D=3.
//
// R10: 32 blocks x 256 threads, 1 wave/SIMD, __launch_bounds__(256,1) ->
// 512-reg unified budget. Each block owns 16 batch rows; each wave owns 4
// hidden tiles with ALL THREE gates' W_hh bf16 A-frags RESIDENT
// (4x3x8x4 = 384 regs, AGPR-eligible) -> zero weight streaming.
//
// Precision (R9 post-mortem): bf16 h-carry drifted to 7 ulp over 512 serial
// steps -> carry h in FP32 REGISTERS (hold[4]); only the GEMM's B operand
// copy of h is bf16 (as in all passing rounds). Encoder hands the decoder
// its final h exactly (fp32 from hold).
//
// Per step: bf B-frags (h, fragment-order LDS) read in two groups of 4 per
// tile-pair (register relief); tiles processed in software-pipelined PAIRS
// so one tile's sigmoid/tanh VALU overlaps the other's MFMA chain.
// x-projection + biases: 3 K=16 MFMAs per tile with C=0 (A-frags in LDS);
// n-gate acc starts from fp32 b_hh bias (LDS broadcast).
//
// h LDS layout FRAGMENT ORDER: h[c][32k+q*8+j] at ((k*4+q)*16+c)*16B+j*2B
// -> B-frag read = lane base + k*1024B immediate, <=2-way aliasing (free).
// Matrix floor: 96 K32 MFMA/wave x ~19.4 cyc = ~1870 cyc/SIMD/step.

#define B_TOT 512
#define T_LEN 256
#define HID 256
#define NBATCH 16
#define NTHREADS 256
#define NBLK 32

#define XT 64                  // shorts per t-slot of staged X (16 c x 4)
#define XSLOTS (T_LEN + 1)
#define HBUF (NBATCH * HID)    // 4096 shorts per h buffer

// dynamic LDS partition (units: shorts)
#define H_OFF   0                      // 2 x 4096
#define AX_OFF  8192                   // 16 tiles x 3 gates x 64 lanes x 4
#define X_OFF   20480                  // 257 x 64 = 16448
#define NHB_OFF 36928                  // 256 floats = 512 shorts
#define SMEM_SHORTS 37440
#define SMEM_BYTES  (SMEM_SHORTS * 2)  // 74880 B

typedef __attribute__((ext_vector_type(4))) float f32x4;
typedef __attribute__((ext_vector_type(8))) short shortx8;
typedef __attribute__((ext_vector_type(4))) short i16x4;
typedef __attribute__((ext_vector_type(4))) unsigned short ushortx4;
typedef __attribute__((ext_vector_type(8))) unsigned short ushortx8;

#if __has_builtin(__builtin_amdgcn_mfma_f32_16x16x16_bf16)
#define HAVE_K16 1
#define MFMA_X(A, B, C) __builtin_amdgcn_mfma_f32_16x16x16_bf16((A), (B), (C), 0, 0, 0)
#elif __has_builtin(__builtin_amdgcn_mfma_f32_16x16x16bf16_1k)
#define HAVE_K16 1
#define MFMA_X(A, B, C) __builtin_amdgcn_mfma_f32_16x16x16bf16_1k((A), (B), (C), 0, 0, 0)
#else
#define HAVE_K16 0
#endif

__device__ __forceinline__ unsigned short f2bf(float x) {
    unsigned u = __float_as_uint(x);
    u += 0x7FFF + ((u >> 16) & 1);   // RNE
    return (unsigned short)(u >> 16);
}
__device__ __forceinline__ float bf2f(unsigned short s) {
    return __uint_as_float(((unsigned)s) << 16);
}
__device__ __forceinline__ float fastrcp(float x) {
#if __has_builtin(__builtin_amdgcn_rcpf)
    return __builtin_amdgcn_rcpf(x);
#else
    return 1.0f / x;
#endif
}
__device__ __forceinline__ float sigmoid_(float x) {
    return fastrcp(1.0f + __expf(-x));
}
__device__ __forceinline__ float tanh_(float x) {
    return 2.0f * fastrcp(1.0f + __expf(-2.0f * x)) - 1.0f;
}

template<int IS_DEC>
__global__ __launch_bounds__(NTHREADS, 1) void gru_persistent(
    const float* __restrict__ X,       // [512][256][3]
    const float* __restrict__ W_hh,    // [768][256] gates r,z,n
    const float* __restrict__ W_ih,    // [768][3]
    const float* __restrict__ b_ih,    // [768]
    const float* __restrict__ b_hh,    // [768]
    const float* __restrict__ h_in,    // dec: [512][256] fp32; enc: null
    const float* __restrict__ noise,   // dec: [512][256]; enc: null
    float* __restrict__ h_out,         // enc: [512][256] fp32; dec: null
    unsigned short* __restrict__ Yout) // dec: [32][256][16][256] bf16
{
    extern __shared__ unsigned short smem[];
    unsigned short* shH  = smem + H_OFF;
    unsigned short* shAx = smem + AX_OFF;
    unsigned short* shX  = smem + X_OFF;
    float*          shNb = (float*)(smem + NHB_OFF);

    const int tid  = threadIdx.x;
    const int g    = blockIdx.x;
    const int w    = tid >> 6;    // wave 0..3; owns tiles w*4 .. w*4+3
    const int lane = tid & 63;
    const int c    = lane & 15;
    const int q    = lane >> 4;

    // ---- stage X into LDS (bf16, shift baked in; slot t = x for step t) ----
    for (int idx = tid; idx < NBATCH * XSLOTS; idx += NTHREADS) {
        int t = idx >> 4, cc = idx & 15;
        int ts = IS_DEC ? (t - 1) : t;
        float x0 = 0.0f, x1 = 0.0f, x2 = 0.0f;
        if (ts >= 0 && ts < T_LEN) {
            const float* xp = X + ((size_t)(g * NBATCH + cc) * T_LEN + ts) * 3;
            x0 = xp[0]; x1 = xp[1]; x2 = xp[2];
        }
        ushortx4 v = {f2bf(x0), f2bf(x1), f2bf(x2), (unsigned short)0x3F80};
        *(ushortx4*)&shX[t * XT + cc * 4] = v;
    }

    // ---- n-gate b_hh bias into LDS (fp32, broadcast-read per tile) ----
    if (tid < 64) {
        f32x4 v = *(const f32x4*)(b_hh + 512 + tid * 4);
        *(f32x4*)&shNb[tid * 4] = v;
    }

    // ---- x/bias A-frags into LDS (q>0 lanes hold zeros) ----
    // kinds: 0 = r (Wih + bih+bhh), 1 = z (Wih + bih+bhh), 2 = nx (Wih + bih)
    #pragma unroll
    for (int i = 0; i < 4; ++i) {
        int ht = w * 4 + i;
        #pragma unroll
        for (int gg = 0; gg < 3; ++gg) {
            short a0 = 0, a1 = 0, a2 = 0, a3 = 0;
            if (q == 0) {
                int row = ((gg == 0) ? 0 : (gg == 1) ? 256 : 512) + ht * 16 + c;
                a0 = (short)f2bf(W_ih[row * 3 + 0]);
                a1 = (short)f2bf(W_ih[row * 3 + 1]);
                a2 = (short)f2bf(W_ih[row * 3 + 2]);
                a3 = (short)f2bf(gg == 2 ? b_ih[row] : (b_ih[row] + b_hh[row]));
            }
            i16x4 v = {a0, a1, a2, a3};
            *(i16x4*)&shAx[((ht * 3 + gg) * 64 + lane) * 4] = v;
        }
    }

    // ---- ALL W_hh A-frags into registers (384, resident whole kernel) ----
    shortx8 Wf[4][3][8];   // [tile][r|z|n][k]
    #pragma unroll
    for (int i = 0; i < 4; ++i) {
        int ht = w * 4 + i;
        #pragma unroll
        for (int gg = 0; gg < 3; ++gg) {
            int row = gg * 256 + ht * 16 + c;
            const float* wp = W_hh + (size_t)row * 256 + q * 8;
            #pragma unroll
            for (int k = 0; k < 8; ++k) {
                const f32x4* p = (const f32x4*)(wp + k * 32);
                f32x4 f0 = p[0];
                f32x4 f1 = p[1];
                shortx8 a;
                a[0] = (short)f2bf(f0[0]); a[1] = (short)f2bf(f0[1]);
                a[2] = (short)f2bf(f0[2]); a[3] = (short)f2bf(f0[3]);
                a[4] = (short)f2bf(f1[0]); a[5] = (short)f2bf(f1[1]);
                a[6] = (short)f2bf(f1[2]); a[7] = (short)f2bf(f1[3]);
                Wf[i][gg][k] = a;
            }
        }
    }

    // ---- epilogue offsets (fragment-order), loop-invariant ----
    int woff[4];
    #pragma unroll
    for (int i = 0; i < 4; ++i) {
        int ht = w * 4 + i;
        int kk = ht >> 1;
        int qq = ((ht & 1) << 1) | (q >> 1);
        woff[i] = ((kk * 4 + qq) * 16 + c) * 8 + (q & 1) * 4;
    }

    // ---- init h0: fp32 carry in regs; bf16 copy into buffer 0 ----
    f32x4 hold[4];
    #pragma unroll
    for (int i = 0; i < 4; ++i) {
        int ht = w * 4 + i;
        int dim0 = ht * 16 + q * 4;
        f32x4 hv = {0.0f, 0.0f, 0.0f, 0.0f};
        if (IS_DEC) {
            int b = g * NBATCH + c;
            f32x4 h0 = *(const f32x4*)(h_in + (size_t)b * HID + dim0);
            f32x4 nz = *(const f32x4*)(noise + (size_t)b * HID + dim0);
            hv = h0 + nz;
        }
        hold[i] = hv;
        ushortx4 hb16 = {f2bf(hv[0]), f2bf(hv[1]), f2bf(hv[2]), f2bf(hv[3])};
        *(ushortx4*)&shH[woff[i]] = hb16;
    }
    __syncthreads();

    const f32x4 zc = {0.0f, 0.0f, 0.0f, 0.0f};
    const int bbase = q * 128 + c * 8;   // lane's B-frag base within a buffer

    // ---- recurrence ----
    for (int t = 0; t < T_LEN; ++t) {
        const unsigned short* hb = shH + (t & 1) * HBUF;
        unsigned short* hn = shH + ((t + 1) & 1) * HBUF;
        const unsigned short* brow = hb + bbase;

        // bx: x B-frag for step t (b64 broadcast; q>0 lanes' A is zero)
#if HAVE_K16
        i16x4 bx = *(const i16x4*)&shX[t * XT + c * 4];
#else
        ushortx4 xv = *(const ushortx4*)&shX[t * XT + c * 4];
        shortx8 bx = (q == 0)
            ? shortx8{(short)xv[0], (short)xv[1], (short)xv[2], (short)xv[3], 0, 0, 0, 0}
            : shortx8{0, 0, 0, 0, 0, 0, 0, 0};
#endif

        // tiles in software-pipelined pairs: init+K for both, then epilogues
        #pragma unroll
        for (int pr = 0; pr < 2; ++pr) {
            f32x4 acc[2][4];   // [pair-slot][r, z, nh, nx]
            // init accs: r/z/nx via K16 x-MFMA (C=0), nh from fp32 b_hh bias
            #pragma unroll
            for (int s = 0; s < 2; ++s) {
                int ht = w * 4 + pr * 2 + s;
                i16x4 axr = *(const i16x4*)&shAx[((ht * 3 + 0) * 64 + lane) * 4];
                i16x4 axz = *(const i16x4*)&shAx[((ht * 3 + 1) * 64 + lane) * 4];
                i16x4 axn = *(const i16x4*)&shAx[((ht * 3 + 2) * 64 + lane) * 4];
#if HAVE_K16
                acc[s][0] = MFMA_X(axr, bx, zc);
                acc[s][1] = MFMA_X(axz, bx, zc);
                acc[s][3] = MFMA_X(axn, bx, zc);
#else
                shortx8 a0 = {axr[0], axr[1], axr[2], axr[3], 0, 0, 0, 0};
                shortx8 a1 = {axz[0], axz[1], axz[2], axz[3], 0, 0, 0, 0};
                shortx8 a2 = {axn[0], axn[1], axn[2], axn[3], 0, 0, 0, 0};
                acc[s][0] = __builtin_amdgcn_mfma_f32_16x16x32_bf16(a0, bx, zc, 0, 0, 0);
                acc[s][1] = __builtin_amdgcn_mfma_f32_16x16x32_bf16(a1, bx, zc, 0, 0, 0);
                acc[s][3] = __builtin_amdgcn_mfma_f32_16x16x32_bf16(a2, bx, zc, 0, 0, 0);
#endif
                acc[s][2] = *(const f32x4*)&shNb[ht * 16 + q * 4];
            }
            // K-chain, bf in two groups of 4 (register relief)
            #pragma unroll
            for (int half = 0; half < 2; ++half) {
                shortx8 bfh[4];
                #pragma unroll
                for (int kk = 0; kk < 4; ++kk)
                    bfh[kk] = *(const shortx8*)(brow + (half * 4 + kk) * 512);
                #pragma unroll
                for (int kk = 0; kk < 4; ++kk) {
                    int k = half * 4 + kk;
                    #pragma unroll
                    for (int s = 0; s < 2; ++s) {
                        int i = pr * 2 + s;
                        acc[s][0] = __builtin_amdgcn_mfma_f32_16x16x32_bf16(Wf[i][0][k], bfh[kk], acc[s][0], 0, 0, 0);
                        acc[s][1] = __builtin_amdgcn_mfma_f32_16x16x32_bf16(Wf[i][1][k], bfh[kk], acc[s][1], 0, 0, 0);
                        acc[s][2] = __builtin_amdgcn_mfma_f32_16x16x32_bf16(Wf[i][2][k], bfh[kk], acc[s][2], 0, 0, 0);
                    }
                }
            }
            // epilogues (VALU) — fp32 carry in regs, exact
            #pragma unroll
            for (int s = 0; s < 2; ++s) {
                int i = pr * 2 + s;
                int ht = w * 4 + i;
                f32x4 hv = hold[i];
                f32x4 ho;
                #pragma unroll
                for (int r = 0; r < 4; ++r) {
                    float rr = sigmoid_(acc[s][0][r]);
                    float zz = sigmoid_(acc[s][1][r]);
                    float nn = tanh_(acc[s][3][r] + rr * acc[s][2][r]);
                    ho[r] = nn + zz * (hv[r] - nn);
                }
                hold[i] = ho;
                ushortx4 hb16 = {f2bf(ho[0]), f2bf(ho[1]), f2bf(ho[2]), f2bf(ho[3])};
                *(ushortx4*)(hn + woff[i]) = hb16;
                if (IS_DEC) {
                    unsigned short* yp = Yout +
                        (((size_t)g * T_LEN + t) * NBATCH + c) * HID + ht * 16 + q * 4;
                    *(ushortx4*)yp = hb16;
                }
            }
        }
        __syncthreads();
    }

    if (!IS_DEC) {
        // hand the decoder the EXACT fp32 final h
        #pragma unroll
        for (int i = 0; i < 4; ++i) {
            int ht = w * 4 + i;
            int dim0 = ht * 16 + q * 4;
            *(f32x4*)(h_out + (size_t)(g * NBATCH + c) * HID + dim0) = hold[i];
        }
    }
}

// out[b][t][d] = sum_h Y[g][t][b16][h] * W_fc[d][h] + b_fc[d]
__global__ __launch_bounds__(256) void proj_kernel(
    const unsigned short* __restrict__ Y, const float* __restrict__ W_fc,
    const float* __restrict__ b_fc, float* __restrict__ out)
{
    int row = blockIdx.x * 256 + threadIdx.x;  // ((g*T + t)*16 + b16)
    int b16 = row & 15;
    int gt = row >> 4;
    int t = gt & (T_LEN - 1);
    int g = gt >> 8;
    const unsigned short* y = Y + (size_t)row * HID;
    float a0 = b_fc[0], a1 = b_fc[1], a2 = b_fc[2];
    #pragma unroll 4
    for (int k8 = 0; k8 < 32; ++k8) {
        ushortx8 v = *(const ushortx8*)(y + k8 * 8);
        #pragma unroll
        for (int j = 0; j < 8; ++j) {
            float f = bf2f(v[j]);
            int k = k8 * 8 + j;
            a0 += f * W_fc[k];          // uniform -> scalar loads
            a1 += f * W_fc[256 + k];
            a2 += f * W_fc[512 + k];
        }
    }
    int batch = g * NBATCH + b16;
    float* o = out + ((size_t)batch * T_LEN + t) * 3;
    o[0] = a0; o[1] = a1; o[2] = a2;
}

extern "C" void kernel_launch(void* const* d_in, const int* in_sizes, int n_in,
                              void* d_out, int out_size, void* d_ws, size_t ws_size,
                              hipStream_t stream)
{
    const float* X_p      = (const float*)d_in[0];
    const float* X_f      = (const float*)d_in[1];
    const float* noise    = (const float*)d_in[2];
    const float* W_ih_enc = (const float*)d_in[3];
    const float* W_hh_enc = (const float*)d_in[4];
    const float* b_ih_enc = (const float*)d_in[5];
    const float* b_hh_enc = (const float*)d_in[6];
    const float* W_ih_dec = (const float*)d_in[7];
    const float* W_hh_dec = (const float*)d_in[8];
    const float* b_ih_dec = (const float*)d_in[9];
    const float* b_hh_dec = (const float*)d_in[10];
    const float* W_fc     = (const float*)d_in[11];
    const float* b_fc     = (const float*)d_in[12];

    // allow >64 KiB dynamic LDS (idempotent; host-side, graph-capture safe)
    (void)hipFuncSetAttribute((const void*)&gru_persistent<0>,
                              hipFuncAttributeMaxDynamicSharedMemorySize, SMEM_BYTES);
    (void)hipFuncSetAttribute((const void*)&gru_persistent<1>,
                              hipFuncAttributeMaxDynamicSharedMemorySize, SMEM_BYTES);

    // ws: [0,512K) h_enc fp32 | [512K, +67.1MB) decoder Y bf16
    float* h_enc = (float*)d_ws;
    unsigned short* Yws = (unsigned short*)((char*)d_ws + (512u << 10));

    hipLaunchKernelGGL((gru_persistent<0>), dim3(NBLK), dim3(NTHREADS), SMEM_BYTES, stream,
        X_p, W_hh_enc, W_ih_enc, b_ih_enc, b_hh_enc,
        (const float*)nullptr, (const float*)nullptr, h_enc,
        (unsigned short*)nullptr);

    hipLaunchKernelGGL((gru_persistent<1>), dim3(NBLK), dim3(NTHREADS), SMEM_BYTES, stream,
        X_f, W_hh_dec, W_ih_dec, b_ih_dec, b_hh_dec,
        h_enc, noise, (float*)nullptr, Yws);

    hipLaunchKernelGGL(proj_kernel, dim3((B_TOT * T_LEN) / 256), dim3(256), 0, stream,
        Yws, W_fc, b_fc, (float*)d_out);
}

// Round 11
// 880.249 us; speedup vs baseline: 1.6012x; 1.6012x over previous
//
#include <hip/hip_runtime.h>

// NetG: seq2seq GRU (enc GRU -> +noise -> dec GRU -> FC head)
// B=512, T=256, H=256, D=3.
//
// R11 = R6 (the measured-best structure: 414 us/GRU) + epilogue VALU diet.
// Persistent-RNN: 32 blocks x 512 threads (8 waves, 2/SIMD -> 256 unified
// regs/wave; compiler puts the 128 resident weight regs in AGPRs, R6 showed
// VGPR_Count=128). Each block owns 16 batch rows for all 256 steps.
//
// R6 counter signature: MfmaUtil(active) 46% + VALUBusy(active) 55% = 100%:
// the 2 lock-stepped waves/SIMD alternate MFMA-phase and VALU-phase
// serially. R7 (intra-step phase split) and R10 (1 wave/SIMD, 512 regs)
// both failed to break this. R11 attacks the VALU phase itself:
//   - gates use raw v_exp_f32 via __builtin_amdgcn_exp2f (if __expf was
//     taking a precise expansion, this is the 3x VALU excess).
//   - n-gate b_hh bias initializes acc[2] as an fp32 register constant
//     (2 fewer x-MFMAs; from R8, orthogonal to R8's prefetch regression).
// Everything else is R6 verbatim: gates z,n resident (128 regs); gate r
// k=0..3 from LDS frags, k=4..7 from global L2 (pre-packed by prep_wr,
// issued at step start -> ~1000 cyc of slack behind the LDS half).
//
// h LDS layout FRAGMENT ORDER: h[c][32k+q*8+j] at ((k*4+q)*16+c)*16B+j*2B
// -> B-frag read = lane base + k*1024B immediate, <=2-way aliasing (free).
// h carried bf16 via LDS (R4-R8 validated: absmax 0.0039, 5x margin).

#define B_TOT 512
#define T_LEN 256
#define HID 256
#define NBATCH 16
#define NTHREADS 512
#define NBLK 32

// LDS partition (units: shorts)
#define WR_OFF 0               // gate-r k=0..3 frags: 16*4*64*8 = 32768
#define H_OFF  32768           // 2 x 4096
#define X_OFF  40960           // 257 x 64 = 16448
#define SMEM_SHORTS 57408
#define SMEM_BYTES  (SMEM_SHORTS * 2)   // 114816 B <= 160 KiB

#define XT 64
#define XSLOTS (T_LEN + 1)
#define HBUF (NBATCH * HID)

typedef __attribute__((ext_vector_type(4))) float f32x4;
typedef __attribute__((ext_vector_type(8))) short shortx8;
typedef __attribute__((ext_vector_type(4))) short i16x4;
typedef __attribute__((ext_vector_type(4))) unsigned short ushortx4;
typedef __attribute__((ext_vector_type(8))) unsigned short ushortx8;

#if __has_builtin(__builtin_amdgcn_mfma_f32_16x16x16_bf16)
#define HAVE_K16 1
#define MFMA_X(A, B, C) __builtin_amdgcn_mfma_f32_16x16x16_bf16((A), (B), (C), 0, 0, 0)
#elif __has_builtin(__builtin_amdgcn_mfma_f32_16x16x16bf16_1k)
#define HAVE_K16 1
#define MFMA_X(A, B, C) __builtin_amdgcn_mfma_f32_16x16x16bf16_1k((A), (B), (C), 0, 0, 0)
#else
#define HAVE_K16 0
#endif

__device__ __forceinline__ unsigned short f2bf(float x) {
    unsigned u = __float_as_uint(x);
    u += 0x7FFF + ((u >> 16) & 1);   // RNE
    return (unsigned short)(u >> 16);
}
__device__ __forceinline__ float bf2f(unsigned short s) {
    return __uint_as_float(((unsigned)s) << 16);
}
__device__ __forceinline__ float fastrcp(float x) {
#if __has_builtin(__builtin_amdgcn_rcpf)
    return __builtin_amdgcn_rcpf(x);
#else
    return 1.0f / x;
#endif
}
// raw v_exp_f32 path: 2^y. e^{-x} = 2^{-x*log2(e)}
__device__ __forceinline__ float exp2raw(float y) {
#if __has_builtin(__builtin_amdgcn_exp2f)
    return __builtin_amdgcn_exp2f(y);
#else
    return __expf(y * 0.69314718056f);
#endif
}
__device__ __forceinline__ float sigmoid_(float x) {
    return fastrcp(1.0f + exp2raw(x * -1.44269504f));
}
__device__ __forceinline__ float tanh_(float x) {
    return 2.0f * fastrcp(1.0f + exp2raw(x * -2.88539008f)) - 1.0f;
}

// Pack gate-r (rows 0..255 of W_hh), K-half k=4..7, into per-lane fragment
// layout: dst[((ht*4+kk)*64+lane)*8+j] = bf16(W[ht*16+(lane&15)][(kk+4)*32+(lane>>4)*8+j])
__global__ __launch_bounds__(256) void prep_wr(
    const float* __restrict__ Whh_enc, const float* __restrict__ Whh_dec,
    unsigned short* __restrict__ wr_enc, unsigned short* __restrict__ wr_dec)
{
    int idx = blockIdx.x * 256 + threadIdx.x;    // 0..8191
    int gru = idx >> 12;
    int rem = idx & 4095;                        // (ht*4+kk)*64 + lane
    int lane = rem & 63;
    int kk = (rem >> 6) & 3;
    int ht = rem >> 8;
    const float* W = gru ? Whh_dec : Whh_enc;
    unsigned short* dst = gru ? wr_dec : wr_enc;
    int row = ht * 16 + (lane & 15);
    int col = (kk + 4) * 32 + (lane >> 4) * 8;
    const float* src = W + (size_t)row * 256 + col;
    ushortx8 v;
    #pragma unroll
    for (int j = 0; j < 8; ++j) v[j] = f2bf(src[j]);
    *(ushortx8*)(dst + (size_t)rem * 8) = v;
}

template<int IS_DEC>
__global__ __launch_bounds__(NTHREADS, 2) void gru_persistent(
    const float* __restrict__ X,       // [512][256][3]
    const float* __restrict__ W_hh,    // [768][256] gates r,z,n
    const float* __restrict__ W_ih,    // [768][3]
    const float* __restrict__ b_ih,    // [768]
    const float* __restrict__ b_hh,    // [768]
    const unsigned short* __restrict__ Wr4, // gate-r k=4..7 frags (prep_wr)
    const float* __restrict__ h_in,    // dec: [512][256] fp32; enc: null
    const float* __restrict__ noise,   // dec: [512][256]; enc: null
    float* __restrict__ h_out,         // enc: [512][256] fp32; dec: null
    unsigned short* __restrict__ Yout) // dec: [32][256][16][256] bf16
{
    extern __shared__ unsigned short smem[];
    unsigned short* shWr = smem + WR_OFF;
    unsigned short* shH  = smem + H_OFF;
    unsigned short* shX  = smem + X_OFF;

    const int tid  = threadIdx.x;
    const int g    = blockIdx.x;
    const int w    = tid >> 6;    // wave; owns hidden tiles {w, w+8}
    const int lane = tid & 63;
    const int c    = lane & 15;
    const int q    = lane >> 4;

    // ---- stage X into LDS (bf16, shift baked in; slot t = x for step t) ----
    for (int idx = tid; idx < NBATCH * XSLOTS; idx += NTHREADS) {
        int t = idx >> 4, cc = idx & 15;
        int ts = IS_DEC ? (t - 1) : t;
        float x0 = 0.0f, x1 = 0.0f, x2 = 0.0f;
        if (ts >= 0 && ts < T_LEN) {
            const float* xp = X + ((size_t)(g * NBATCH + cc) * T_LEN + ts) * 3;
            x0 = xp[0]; x1 = xp[1]; x2 = xp[2];
        }
        ushortx4 v = {f2bf(x0), f2bf(x1), f2bf(x2), (unsigned short)0x3F80};
        *(ushortx4*)&shX[t * XT + cc * 4] = v;
    }

    // ---- gate-r k=0..3 frags -> LDS (each wave stages its 2 tiles) ----
    #pragma unroll
    for (int hti = 0; hti < 2; ++hti) {
        int ht = w + hti * 8;
        int row = ht * 16 + c;                      // gate r
        const float* wp = W_hh + (size_t)row * 256 + q * 8;
        #pragma unroll
        for (int k = 0; k < 4; ++k) {
            const f32x4* p = (const f32x4*)(wp + k * 32);
            f32x4 f0 = p[0];
            f32x4 f1 = p[1];
            shortx8 a;
            a[0] = (short)f2bf(f0[0]); a[1] = (short)f2bf(f0[1]);
            a[2] = (short)f2bf(f0[2]); a[3] = (short)f2bf(f0[3]);
            a[4] = (short)f2bf(f1[0]); a[5] = (short)f2bf(f1[1]);
            a[6] = (short)f2bf(f1[2]); a[7] = (short)f2bf(f1[3]);
            *(shortx8*)&shWr[((ht * 4 + k) * 64 + lane) * 8] = a;
        }
    }

    // ---- gates z,n A-frags into registers (128 regs, resident) ----
    shortx8 Wf[2][2][8];   // [hti][z|n][k]
    #pragma unroll
    for (int hti = 0; hti < 2; ++hti) {
        int ht = w + hti * 8;
        #pragma unroll
        for (int gg = 0; gg < 2; ++gg) {
            int row = (gg + 1) * 256 + ht * 16 + c;
            const float* wp = W_hh + (size_t)row * 256 + q * 8;
            #pragma unroll
            for (int k = 0; k < 8; ++k) {
                const f32x4* p = (const f32x4*)(wp + k * 32);
                f32x4 f0 = p[0];
                f32x4 f1 = p[1];
                shortx8 a;
                a[0] = (short)f2bf(f0[0]); a[1] = (short)f2bf(f0[1]);
                a[2] = (short)f2bf(f0[2]); a[3] = (short)f2bf(f0[3]);
                a[4] = (short)f2bf(f1[0]); a[5] = (short)f2bf(f1[1]);
                a[6] = (short)f2bf(f1[2]); a[7] = (short)f2bf(f1[3]);
                Wf[hti][gg][k] = a;
            }
        }
    }

    // ---- x/bias A-frags (q==0 lanes carry data; others MUST be zero) ----
    // kinds: 0 = r (Wih + bih+bhh), 1 = z (Wih + bih+bhh), 2 = nx (Wih + bih)
#if HAVE_K16
    i16x4 ax[2][3];
#else
    shortx8 ax[2][3];
#endif
    #pragma unroll
    for (int hti = 0; hti < 2; ++hti) {
        int ht = w + hti * 8;
        int rr = ht * 16 + c;
        int rowr = rr, rowz = 256 + rr, rown = 512 + rr;
        short r0 = 0, r1 = 0, r2 = 0, r3 = 0, z0 = 0, z1 = 0, z2 = 0, z3 = 0;
        short n0 = 0, n1 = 0, n2 = 0, n3 = 0;
        if (q == 0) {
            r0 = (short)f2bf(W_ih[rowr * 3 + 0]);
            r1 = (short)f2bf(W_ih[rowr * 3 + 1]);
            r2 = (short)f2bf(W_ih[rowr * 3 + 2]);
            r3 = (short)f2bf(b_ih[rowr] + b_hh[rowr]);
            z0 = (short)f2bf(W_ih[rowz * 3 + 0]);
            z1 = (short)f2bf(W_ih[rowz * 3 + 1]);
            z2 = (short)f2bf(W_ih[rowz * 3 + 2]);
            z3 = (short)f2bf(b_ih[rowz] + b_hh[rowz]);
            n0 = (short)f2bf(W_ih[rown * 3 + 0]);
            n1 = (short)f2bf(W_ih[rown * 3 + 1]);
            n2 = (short)f2bf(W_ih[rown * 3 + 2]);
            n3 = (short)f2bf(b_ih[rown]);
        }
#if HAVE_K16
        ax[hti][0] = i16x4{r0, r1, r2, r3};
        ax[hti][1] = i16x4{z0, z1, z2, z3};
        ax[hti][2] = i16x4{n0, n1, n2, n3};
#else
        ax[hti][0] = shortx8{r0, r1, r2, r3, 0, 0, 0, 0};
        ax[hti][1] = shortx8{z0, z1, z2, z3, 0, 0, 0, 0};
        ax[hti][2] = shortx8{n0, n1, n2, n3, 0, 0, 0, 0};
#endif
    }

    // ---- nh-bias register constants (b_hh n-gate, this lane's D rows) ----
    f32x4 nhb[2];
    #pragma unroll
    for (int hti = 0; hti < 2; ++hti) {
        int ht = w + hti * 8;
        nhb[hti] = *(const f32x4*)(b_hh + 512 + ht * 16 + q * 4);
    }

    // ---- epilogue offsets (fragment-order), loop-invariant ----
    int woff[2];
    #pragma unroll
    for (int hti = 0; hti < 2; ++hti) {
        int ht = w + hti * 8;
        int kk = ht >> 1;
        int qq = ((ht & 1) << 1) | (q >> 1);
        woff[hti] = ((kk * 4 + qq) * 16 + c) * 8 + (q & 1) * 4;
    }

    // ---- init h0 bf16 into buffer 0 ----
    #pragma unroll
    for (int hti = 0; hti < 2; ++hti) {
        int ht = w + hti * 8;
        int dim0 = ht * 16 + q * 4;
        f32x4 hv = {0.0f, 0.0f, 0.0f, 0.0f};
        if (IS_DEC) {
            int b = g * NBATCH + c;
            f32x4 h0 = *(const f32x4*)(h_in + (size_t)b * HID + dim0);
            f32x4 nz = *(const f32x4*)(noise + (size_t)b * HID + dim0);
            hv = h0 + nz;
        }
        ushortx4 hb16 = {f2bf(hv[0]), f2bf(hv[1]), f2bf(hv[2]), f2bf(hv[3])};
        *(ushortx4*)&shH[woff[hti]] = hb16;
    }
    __syncthreads();

    const f32x4 zc = {0.0f, 0.0f, 0.0f, 0.0f};

    // ---- x-step for t=0 (C = inline 0 initializes acc r/z/nx) ----
    f32x4 acc[2][4];  // [hti][r, z, nh, nx]
    {
#if HAVE_K16
        i16x4 bx = *(const i16x4*)&shX[c * 4];
        #pragma unroll
        for (int hti = 0; hti < 2; ++hti) {
            acc[hti][0] = MFMA_X(ax[hti][0], bx, zc);
            acc[hti][1] = MFMA_X(ax[hti][1], bx, zc);
            acc[hti][3] = MFMA_X(ax[hti][2], bx, zc);
        }
#else
        ushortx4 xv = *(const ushortx4*)&shX[c * 4];
        shortx8 bx = (q == 0)
            ? shortx8{(short)xv[0], (short)xv[1], (short)xv[2], (short)xv[3], 0, 0, 0, 0}
            : shortx8{0, 0, 0, 0, 0, 0, 0, 0};
        #pragma unroll
        for (int hti = 0; hti < 2; ++hti) {
            acc[hti][0] = __builtin_amdgcn_mfma_f32_16x16x32_bf16(ax[hti][0], bx, zc, 0, 0, 0);
            acc[hti][1] = __builtin_amdgcn_mfma_f32_16x16x32_bf16(ax[hti][1], bx, zc, 0, 0, 0);
            acc[hti][3] = __builtin_amdgcn_mfma_f32_16x16x32_bf16(ax[hti][2], bx, zc, 0, 0, 0);
        }
#endif
    }

    const int bbase = q * 128 + c * 8;   // lane's B-frag base within a buffer
    const unsigned short* ab0 = shWr + ((size_t)(w * 4) * 64 + lane) * 8;
    const unsigned short* ab1 = shWr + ((size_t)((w + 8) * 4) * 64 + lane) * 8;
    const unsigned short* gb0 = Wr4 + ((size_t)(w * 4) * 64 + lane) * 8;
    const unsigned short* gb1 = Wr4 + ((size_t)((w + 8) * 4) * 64 + lane) * 8;

    // ---- recurrence ----
    for (int t = 0; t < T_LEN; ++t) {
        const unsigned short* hb = shH + (t & 1) * HBUF;
        unsigned short* hn = shH + ((t + 1) & 1) * HBUF;
        const unsigned short* brow = hb + bbase;

        // gate-r k=4..7 from global: issued at step start, consumed after
        // the LDS half (~1000 cyc of slack — R6's proven timing)
        shortx8 gr0[4], gr1[4];
        #pragma unroll
        for (int kk = 0; kk < 4; ++kk) {
            gr0[kk] = *(const shortx8*)(gb0 + (kk + 0) * 512 + 0);
            gr1[kk] = *(const shortx8*)(gb1 + (kk + 0) * 512 + 0);
        }

        // h_t carry slots (b64 ds reads, needed only at the epilogue)
        ushortx4 hu0 = *(const ushortx4*)(hb + woff[0]);
        ushortx4 hu1 = *(const ushortx4*)(hb + woff[1]);

        // n-gate hidden accumulators start from the b_hh bias constants
        acc[0][2] = nhb[0];
        acc[1][2] = nhb[1];

        // k=0..3: gate-r from LDS
        #pragma unroll
        for (int k = 0; k < 4; ++k) {
            shortx8 bf  = *(const shortx8*)(brow + k * 512);
            shortx8 ar0 = *(const shortx8*)(ab0 + k * 512);
            shortx8 ar1 = *(const shortx8*)(ab1 + k * 512);
            acc[0][0] = __builtin_amdgcn_mfma_f32_16x16x32_bf16(ar0,         bf, acc[0][0], 0, 0, 0);
            acc[1][0] = __builtin_amdgcn_mfma_f32_16x16x32_bf16(ar1,         bf, acc[1][0], 0, 0, 0);
            acc[0][1] = __builtin_amdgcn_mfma_f32_16x16x32_bf16(Wf[0][0][k], bf, acc[0][1], 0, 0, 0);
            acc[1][1] = __builtin_amdgcn_mfma_f32_16x16x32_bf16(Wf[1][0][k], bf, acc[1][1], 0, 0, 0);
            acc[0][2] = __builtin_amdgcn_mfma_f32_16x16x32_bf16(Wf[0][1][k], bf, acc[0][2], 0, 0, 0);
            acc[1][2] = __builtin_amdgcn_mfma_f32_16x16x32_bf16(Wf[1][1][k], bf, acc[1][2], 0, 0, 0);
        }
        // k=4..7: gate-r from the global prefetch
        #pragma unroll
        for (int k = 4; k < 8; ++k) {
            shortx8 bf = *(const shortx8*)(brow + k * 512);
            acc[0][0] = __builtin_amdgcn_mfma_f32_16x16x32_bf16(gr0[k - 4],  bf, acc[0][0], 0, 0, 0);
            acc[1][0] = __builtin_amdgcn_mfma_f32_16x16x32_bf16(gr1[k - 4],  bf, acc[1][0], 0, 0, 0);
            acc[0][1] = __builtin_amdgcn_mfma_f32_16x16x32_bf16(Wf[0][0][k], bf, acc[0][1], 0, 0, 0);
            acc[1][1] = __builtin_amdgcn_mfma_f32_16x16x32_bf16(Wf[1][0][k], bf, acc[1][1], 0, 0, 0);
            acc[0][2] = __builtin_amdgcn_mfma_f32_16x16x32_bf16(Wf[0][1][k], bf, acc[0][2], 0, 0, 0);
            acc[1][2] = __builtin_amdgcn_mfma_f32_16x16x32_bf16(Wf[1][1][k], bf, acc[1][2], 0, 0, 0);
        }

        // ---- epilogue: D[row=q*4+r][col=c]; h carried bf16 via LDS ----
        #pragma unroll
        for (int hti = 0; hti < 2; ++hti) {
            ushortx4 hu = hti ? hu1 : hu0;
            f32x4 ho;
            #pragma unroll
            for (int r = 0; r < 4; ++r) {
                float hv = bf2f(hu[r]);
                float rr = sigmoid_(acc[hti][0][r]);
                float zz = sigmoid_(acc[hti][1][r]);
                float nn = tanh_(acc[hti][3][r] + rr * acc[hti][2][r]);
                ho[r] = nn + zz * (hv - nn);
            }
            ushortx4 hb16 = {f2bf(ho[0]), f2bf(ho[1]), f2bf(ho[2]), f2bf(ho[3])};
            *(ushortx4*)(hn + woff[hti]) = hb16;
            if (IS_DEC) {
                int ht = w + hti * 8;
                unsigned short* yp = Yout +
                    (((size_t)g * T_LEN + t) * NBATCH + c) * HID + ht * 16 + q * 4;
                *(ushortx4*)yp = hb16;
            }
        }

        // ---- x-step for t+1 (independent of h -> fills barrier shadow) ----
        {
#if HAVE_K16
            i16x4 bx = *(const i16x4*)&shX[(t + 1) * XT + c * 4];
            #pragma unroll
            for (int hti = 0; hti < 2; ++hti) {
                acc[hti][0] = MFMA_X(ax[hti][0], bx, zc);
                acc[hti][1] = MFMA_X(ax[hti][1], bx, zc);
                acc[hti][3] = MFMA_X(ax[hti][2], bx, zc);
            }
#else
            ushortx4 xv = *(const ushortx4*)&shX[(t + 1) * XT + c * 4];
            shortx8 bx = (q == 0)
                ? shortx8{(short)xv[0], (short)xv[1], (short)xv[2], (short)xv[3], 0, 0, 0, 0}
                : shortx8{0, 0, 0, 0, 0, 0, 0, 0};
            #pragma unroll
            for (int hti = 0; hti < 2; ++hti) {
                acc[hti][0] = __builtin_amdgcn_mfma_f32_16x16x32_bf16(ax[hti][0], bx, zc, 0, 0, 0);
                acc[hti][1] = __builtin_amdgcn_mfma_f32_16x16x32_bf16(ax[hti][1], bx, zc, 0, 0, 0);
                acc[hti][3] = __builtin_amdgcn_mfma_f32_16x16x32_bf16(ax[hti][2], bx, zc, 0, 0, 0);
            }
#endif
        }
        __syncthreads();
    }

    if (!IS_DEC) {
        // final h in buffer 0 (T even); bf16 -> fp32 for the decoder
        #pragma unroll
        for (int hti = 0; hti < 2; ++hti) {
            int ht = w + hti * 8;
            int dim0 = ht * 16 + q * 4;
            ushortx4 hu = *(const ushortx4*)(shH + woff[hti]);
            f32x4 o = {bf2f(hu[0]), bf2f(hu[1]), bf2f(hu[2]), bf2f(hu[3])};
            *(f32x4*)(h_out + (size_t)(g * NBATCH + c) * HID + dim0) = o;
        }
    }
}

// out[b][t][d] = sum_h Y[g][t][b16][h] * W_fc[d][h] + b_fc[d]
__global__ __launch_bounds__(256) void proj_kernel(
    const unsigned short* __restrict__ Y, const float* __restrict__ W_fc,
    const float* __restrict__ b_fc, float* __restrict__ out)
{
    int row = blockIdx.x * 256 + threadIdx.x;  // ((g*T + t)*16 + b16)
    int b16 = row & 15;
    int gt = row >> 4;
    int t = gt & (T_LEN - 1);
    int g = gt >> 8;
    const unsigned short* y = Y + (size_t)row * HID;
    float a0 = b_fc[0], a1 = b_fc[1], a2 = b_fc[2];
    #pragma unroll 4
    for (int k8 = 0; k8 < 32; ++k8) {
        ushortx8 v = *(const ushortx8*)(y + k8 * 8);
        #pragma unroll
        for (int j = 0; j < 8; ++j) {
            float f = bf2f(v[j]);
            int k = k8 * 8 + j;
            a0 += f * W_fc[k];          // uniform -> scalar loads
            a1 += f * W_fc[256 + k];
            a2 += f * W_fc[512 + k];
        }
    }
    int batch = g * NBATCH + b16;
    float* o = out + ((size_t)batch * T_LEN + t) * 3;
    o[0] = a0; o[1] = a1; o[2] = a2;
}

extern "C" void kernel_launch(void* const* d_in, const int* in_sizes, int n_in,
                              void* d_out, int out_size, void* d_ws, size_t ws_size,
                              hipStream_t stream)
{
    const float* X_p      = (const float*)d_in[0];
    const float* X_f      = (const float*)d_in[1];
    const float* noise    = (const float*)d_in[2];
    const float* W_ih_enc = (const float*)d_in[3];
    const float* W_hh_enc = (const float*)d_in[4];
    const float* b_ih_enc = (const float*)d_in[5];
    const float* b_hh_enc = (const float*)d_in[6];
    const float* W_ih_dec = (const float*)d_in[7];
    const float* W_hh_dec = (const float*)d_in[8];
    const float* b_ih_dec = (const float*)d_in[9];
    const float* b_hh_dec = (const float*)d_in[10];
    const float* W_fc     = (const float*)d_in[11];
    const float* b_fc     = (const float*)d_in[12];

    // allow >64 KiB dynamic LDS (idempotent; host-side, graph-capture safe)
    (void)hipFuncSetAttribute((const void*)&gru_persistent<0>,
                              hipFuncAttributeMaxDynamicSharedMemorySize, SMEM_BYTES);
    (void)hipFuncSetAttribute((const void*)&gru_persistent<1>,
                              hipFuncAttributeMaxDynamicSharedMemorySize, SMEM_BYTES);

    // ws: [0,512K) h_enc fp32 | [512K,576K) Wr_enc | [576K,640K) Wr_dec |
    //     [640K, +67.1MB) decoder Y bf16
    float* h_enc = (float*)d_ws;
    unsigned short* wr_enc = (unsigned short*)((char*)d_ws + (512u << 10));
    unsigned short* wr_dec = (unsigned short*)((char*)d_ws + (576u << 10));
    unsigned short* Yws    = (unsigned short*)((char*)d_ws + (640u << 10));

    hipLaunchKernelGGL(prep_wr, dim3(32), dim3(256), 0, stream,
        W_hh_enc, W_hh_dec, wr_enc, wr_dec);

    hipLaunchKernelGGL((gru_persistent<0>), dim3(NBLK), dim3(NTHREADS), SMEM_BYTES, stream,
        X_p, W_hh_enc, W_ih_enc, b_ih_enc, b_hh_enc, wr_enc,
        (const float*)nullptr, (const float*)nullptr, h_enc,
        (unsigned short*)nullptr);

    hipLaunchKernelGGL((gru_persistent<1>), dim3(NBLK), dim3(NTHREADS), SMEM_BYTES, stream,
        X_f, W_hh_dec, W_ih_dec, b_ih_dec, b_hh_dec, wr_dec,
        h_enc, noise, (float*)nullptr, Yws);

    hipLaunchKernelGGL(proj_kernel, dim3((B_TOT * T_LEN) / 256), dim3(256), 0, stream,
        Yws, W_fc, b_fc, (float*)d_out);
}

// Round 12
// 851.629 us; speedup vs baseline: 1.6550x; 1.0336x over previous
//
#include <hip/hip_runtime.h>

// NetG: seq2seq GRU (enc GRU -> +noise -> dec GRU -> FC head)
// B=512, T=256, H=256, D=3.
//
// R12 = R11/R6 structure (measured-best: 413 us/GRU) + VALU-phase diet:
//   1. h carried in FP32 REGISTERS (hold[2]): removes per-step hu ds-reads
//      + bf2f unpacks; exact carry (R9 lesson); encoder->decoder handoff
//      is exact fp32. GEMM's B operand stays bf16 (validated numerics).
//   2. Incremental pointers for the decoder Y store and the x-slot index:
//      kills per-step 64-bit address-mul chains (prime suspect for the
//      ~700 cyc/SIMD of VALUBusy above op-count floor).
//   3. Tile-interleaved tail: epilogue(tile i) immediately followed by that
//      tile's x-step MFMA re-init, so 3 MFMAs issue under each trans chain.
// Frozen from R6/R11: 32 blocks x 512 threads (8 waves, 2/SIMD); gates z,n
// resident 128 regs; gate r k=0..3 LDS frags / k=4..7 global L2 (prep_wr,
// issued at step start, consumed after the LDS half); fragment-order h in
// LDS (lane base + k*1024B, <=2-way aliasing); native v_exp gates.

#define B_TOT 512
#define T_LEN 256
#define HID 256
#define NBATCH 16
#define NTHREADS 512
#define NBLK 32

// LDS partition (units: shorts)
#define WR_OFF 0               // gate-r k=0..3 frags: 16*4*64*8 = 32768
#define H_OFF  32768           // 2 x 4096
#define X_OFF  40960           // 257 x 64 = 16448
#define SMEM_SHORTS 57408
#define SMEM_BYTES  (SMEM_SHORTS * 2)   // 114816 B <= 160 KiB

#define XT 64
#define XSLOTS (T_LEN + 1)
#define HBUF (NBATCH * HID)

typedef __attribute__((ext_vector_type(4))) float f32x4;
typedef __attribute__((ext_vector_type(8))) short shortx8;
typedef __attribute__((ext_vector_type(4))) short i16x4;
typedef __attribute__((ext_vector_type(4))) unsigned short ushortx4;
typedef __attribute__((ext_vector_type(8))) unsigned short ushortx8;

#if __has_builtin(__builtin_amdgcn_mfma_f32_16x16x16_bf16)
#define HAVE_K16 1
#define MFMA_X(A, B, C) __builtin_amdgcn_mfma_f32_16x16x16_bf16((A), (B), (C), 0, 0, 0)
#elif __has_builtin(__builtin_amdgcn_mfma_f32_16x16x16bf16_1k)
#define HAVE_K16 1
#define MFMA_X(A, B, C) __builtin_amdgcn_mfma_f32_16x16x16bf16_1k((A), (B), (C), 0, 0, 0)
#else
#define HAVE_K16 0
#endif

__device__ __forceinline__ unsigned short f2bf(float x) {
    unsigned u = __float_as_uint(x);
    u += 0x7FFF + ((u >> 16) & 1);   // RNE
    return (unsigned short)(u >> 16);
}
__device__ __forceinline__ float bf2f(unsigned short s) {
    return __uint_as_float(((unsigned)s) << 16);
}
__device__ __forceinline__ float fastrcp(float x) {
#if __has_builtin(__builtin_amdgcn_rcpf)
    return __builtin_amdgcn_rcpf(x);
#else
    return 1.0f / x;
#endif
}
__device__ __forceinline__ float exp2raw(float y) {
#if __has_builtin(__builtin_amdgcn_exp2f)
    return __builtin_amdgcn_exp2f(y);
#else
    return __expf(y * 0.69314718056f);
#endif
}
__device__ __forceinline__ float sigmoid_(float x) {
    return fastrcp(1.0f + exp2raw(x * -1.44269504f));
}
__device__ __forceinline__ float tanh_(float x) {
    return 2.0f * fastrcp(1.0f + exp2raw(x * -2.88539008f)) - 1.0f;
}

// Pack gate-r (rows 0..255 of W_hh), K-half k=4..7, into per-lane fragment
// layout: dst[((ht*4+kk)*64+lane)*8+j] = bf16(W[ht*16+(lane&15)][(kk+4)*32+(lane>>4)*8+j])
__global__ __launch_bounds__(256) void prep_wr(
    const float* __restrict__ Whh_enc, const float* __restrict__ Whh_dec,
    unsigned short* __restrict__ wr_enc, unsigned short* __restrict__ wr_dec)
{
    int idx = blockIdx.x * 256 + threadIdx.x;    // 0..8191
    int gru = idx >> 12;
    int rem = idx & 4095;                        // (ht*4+kk)*64 + lane
    int lane = rem & 63;
    int kk = (rem >> 6) & 3;
    int ht = rem >> 8;
    const float* W = gru ? Whh_dec : Whh_enc;
    unsigned short* dst = gru ? wr_dec : wr_enc;
    int row = ht * 16 + (lane & 15);
    int col = (kk + 4) * 32 + (lane >> 4) * 8;
    const float* src = W + (size_t)row * 256 + col;
    ushortx8 v;
    #pragma unroll
    for (int j = 0; j < 8; ++j) v[j] = f2bf(src[j]);
    *(ushortx8*)(dst + (size_t)rem * 8) = v;
}

template<int IS_DEC>
__global__ __launch_bounds__(NTHREADS, 2) void gru_persistent(
    const float* __restrict__ X,       // [512][256][3]
    const float* __restrict__ W_hh,    // [768][256] gates r,z,n
    const float* __restrict__ W_ih,    // [768][3]
    const float* __restrict__ b_ih,    // [768]
    const float* __restrict__ b_hh,    // [768]
    const unsigned short* __restrict__ Wr4, // gate-r k=4..7 frags (prep_wr)
    const float* __restrict__ h_in,    // dec: [512][256] fp32; enc: null
    const float* __restrict__ noise,   // dec: [512][256]; enc: null
    float* __restrict__ h_out,         // enc: [512][256] fp32; dec: null
    unsigned short* __restrict__ Yout) // dec: [32][256][16][256] bf16
{
    extern __shared__ unsigned short smem[];
    unsigned short* shWr = smem + WR_OFF;
    unsigned short* shH  = smem + H_OFF;
    unsigned short* shX  = smem + X_OFF;

    const int tid  = threadIdx.x;
    const int g    = blockIdx.x;
    const int w    = tid >> 6;    // wave; owns hidden tiles {w, w+8}
    const int lane = tid & 63;
    const int c    = lane & 15;
    const int q    = lane >> 4;

    // ---- stage X into LDS (bf16, shift baked in; slot t = x for step t) ----
    for (int idx = tid; idx < NBATCH * XSLOTS; idx += NTHREADS) {
        int t = idx >> 4, cc = idx & 15;
        int ts = IS_DEC ? (t - 1) : t;
        float x0 = 0.0f, x1 = 0.0f, x2 = 0.0f;
        if (ts >= 0 && ts < T_LEN) {
            const float* xp = X + ((size_t)(g * NBATCH + cc) * T_LEN + ts) * 3;
            x0 = xp[0]; x1 = xp[1]; x2 = xp[2];
        }
        ushortx4 v = {f2bf(x0), f2bf(x1), f2bf(x2), (unsigned short)0x3F80};
        *(ushortx4*)&shX[t * XT + cc * 4] = v;
    }

    // ---- gate-r k=0..3 frags -> LDS (each wave stages its 2 tiles) ----
    #pragma unroll
    for (int hti = 0; hti < 2; ++hti) {
        int ht = w + hti * 8;
        int row = ht * 16 + c;                      // gate r
        const float* wp = W_hh + (size_t)row * 256 + q * 8;
        #pragma unroll
        for (int k = 0; k < 4; ++k) {
            const f32x4* p = (const f32x4*)(wp + k * 32);
            f32x4 f0 = p[0];
            f32x4 f1 = p[1];
            shortx8 a;
            a[0] = (short)f2bf(f0[0]); a[1] = (short)f2bf(f0[1]);
            a[2] = (short)f2bf(f0[2]); a[3] = (short)f2bf(f0[3]);
            a[4] = (short)f2bf(f1[0]); a[5] = (short)f2bf(f1[1]);
            a[6] = (short)f2bf(f1[2]); a[7] = (short)f2bf(f1[3]);
            *(shortx8*)&shWr[((ht * 4 + k) * 64 + lane) * 8] = a;
        }
    }

    // ---- gates z,n A-frags into registers (128 regs, resident) ----
    shortx8 Wf[2][2][8];   // [hti][z|n][k]
    #pragma unroll
    for (int hti = 0; hti < 2; ++hti) {
        int ht = w + hti * 8;
        #pragma unroll
        for (int gg = 0; gg < 2; ++gg) {
            int row = (gg + 1) * 256 + ht * 16 + c;
            const float* wp = W_hh + (size_t)row * 256 + q * 8;
            #pragma unroll
            for (int k = 0; k < 8; ++k) {
                const f32x4* p = (const f32x4*)(wp + k * 32);
                f32x4 f0 = p[0];
                f32x4 f1 = p[1];
                shortx8 a;
                a[0] = (short)f2bf(f0[0]); a[1] = (short)f2bf(f0[1]);
                a[2] = (short)f2bf(f0[2]); a[3] = (short)f2bf(f0[3]);
                a[4] = (short)f2bf(f1[0]); a[5] = (short)f2bf(f1[1]);
                a[6] = (short)f2bf(f1[2]); a[7] = (short)f2bf(f1[3]);
                Wf[hti][gg][k] = a;
            }
        }
    }

    // ---- x/bias A-frags (q==0 lanes carry data; others MUST be zero) ----
    // kinds: 0 = r (Wih + bih+bhh), 1 = z (Wih + bih+bhh), 2 = nx (Wih + bih)
#if HAVE_K16
    i16x4 ax[2][3];
#else
    shortx8 ax[2][3];
#endif
    #pragma unroll
    for (int hti = 0; hti < 2; ++hti) {
        int ht = w + hti * 8;
        int rr = ht * 16 + c;
        int rowr = rr, rowz = 256 + rr, rown = 512 + rr;
        short r0 = 0, r1 = 0, r2 = 0, r3 = 0, z0 = 0, z1 = 0, z2 = 0, z3 = 0;
        short n0 = 0, n1 = 0, n2 = 0, n3 = 0;
        if (q == 0) {
            r0 = (short)f2bf(W_ih[rowr * 3 + 0]);
            r1 = (short)f2bf(W_ih[rowr * 3 + 1]);
            r2 = (short)f2bf(W_ih[rowr * 3 + 2]);
            r3 = (short)f2bf(b_ih[rowr] + b_hh[rowr]);
            z0 = (short)f2bf(W_ih[rowz * 3 + 0]);
            z1 = (short)f2bf(W_ih[rowz * 3 + 1]);
            z2 = (short)f2bf(W_ih[rowz * 3 + 2]);
            z3 = (short)f2bf(b_ih[rowz] + b_hh[rowz]);
            n0 = (short)f2bf(W_ih[rown * 3 + 0]);
            n1 = (short)f2bf(W_ih[rown * 3 + 1]);
            n2 = (short)f2bf(W_ih[rown * 3 + 2]);
            n3 = (short)f2bf(b_ih[rown]);
        }
#if HAVE_K16
        ax[hti][0] = i16x4{r0, r1, r2, r3};
        ax[hti][1] = i16x4{z0, z1, z2, z3};
        ax[hti][2] = i16x4{n0, n1, n2, n3};
#else
        ax[hti][0] = shortx8{r0, r1, r2, r3, 0, 0, 0, 0};
        ax[hti][1] = shortx8{z0, z1, z2, z3, 0, 0, 0, 0};
        ax[hti][2] = shortx8{n0, n1, n2, n3, 0, 0, 0, 0};
#endif
    }

    // ---- nh-bias register constants (b_hh n-gate, this lane's D rows) ----
    f32x4 nhb[2];
    #pragma unroll
    for (int hti = 0; hti < 2; ++hti) {
        int ht = w + hti * 8;
        nhb[hti] = *(const f32x4*)(b_hh + 512 + ht * 16 + q * 4);
    }

    // ---- epilogue offsets (fragment-order), loop-invariant ----
    int woff[2];
    #pragma unroll
    for (int hti = 0; hti < 2; ++hti) {
        int ht = w + hti * 8;
        int kk = ht >> 1;
        int qq = ((ht & 1) << 1) | (q >> 1);
        woff[hti] = ((kk * 4 + qq) * 16 + c) * 8 + (q & 1) * 4;
    }

    // ---- init h0: fp32 carry in regs; bf16 copy into buffer 0 ----
    f32x4 hold[2];
    #pragma unroll
    for (int hti = 0; hti < 2; ++hti) {
        int ht = w + hti * 8;
        int dim0 = ht * 16 + q * 4;
        f32x4 hv = {0.0f, 0.0f, 0.0f, 0.0f};
        if (IS_DEC) {
            int b = g * NBATCH + c;
            f32x4 h0 = *(const f32x4*)(h_in + (size_t)b * HID + dim0);
            f32x4 nz = *(const f32x4*)(noise + (size_t)b * HID + dim0);
            hv = h0 + nz;
        }
        hold[hti] = hv;
        ushortx4 hb16 = {f2bf(hv[0]), f2bf(hv[1]), f2bf(hv[2]), f2bf(hv[3])};
        *(ushortx4*)&shH[woff[hti]] = hb16;
    }

    // ---- incremental decoder Y pointers (step stride = 4096 shorts) ----
    unsigned short* yp[2];
    #pragma unroll
    for (int hti = 0; hti < 2; ++hti) {
        int ht = w + hti * 8;
        yp[hti] = Yout + ((size_t)g * T_LEN * NBATCH + c) * HID + ht * 16 + q * 4;
    }
    __syncthreads();

    const f32x4 zc = {0.0f, 0.0f, 0.0f, 0.0f};

    // ---- x-step for t=0 (C = inline 0 initializes acc r/z/nx) ----
    f32x4 acc[2][4];  // [hti][r, z, nh, nx]
    {
#if HAVE_K16
        i16x4 bx = *(const i16x4*)&shX[c * 4];
        #pragma unroll
        for (int hti = 0; hti < 2; ++hti) {
            acc[hti][0] = MFMA_X(ax[hti][0], bx, zc);
            acc[hti][1] = MFMA_X(ax[hti][1], bx, zc);
            acc[hti][3] = MFMA_X(ax[hti][2], bx, zc);
        }
#else
        ushortx4 xv = *(const ushortx4*)&shX[c * 4];
        shortx8 bx = (q == 0)
            ? shortx8{(short)xv[0], (short)xv[1], (short)xv[2], (short)xv[3], 0, 0, 0, 0}
            : shortx8{0, 0, 0, 0, 0, 0, 0, 0};
        #pragma unroll
        for (int hti = 0; hti < 2; ++hti) {
            acc[hti][0] = __builtin_amdgcn_mfma_f32_16x16x32_bf16(ax[hti][0], bx, zc, 0, 0, 0);
            acc[hti][1] = __builtin_amdgcn_mfma_f32_16x16x32_bf16(ax[hti][1], bx, zc, 0, 0, 0);
            acc[hti][3] = __builtin_amdgcn_mfma_f32_16x16x32_bf16(ax[hti][2], bx, zc, 0, 0, 0);
        }
#endif
    }

    const int bbase = q * 128 + c * 8;   // lane's B-frag base within a buffer
    const unsigned short* ab0 = shWr + ((size_t)(w * 4) * 64 + lane) * 8;
    const unsigned short* ab1 = shWr + ((size_t)((w + 8) * 4) * 64 + lane) * 8;
    const unsigned short* gb0 = Wr4 + ((size_t)(w * 4) * 64 + lane) * 8;
    const unsigned short* gb1 = Wr4 + ((size_t)((w + 8) * 4) * 64 + lane) * 8;

    int xidx = XT + c * 4;   // x slot for step t+1 (incremental)

    // ---- recurrence ----
    for (int t = 0; t < T_LEN; ++t) {
        const unsigned short* hb = shH + (t & 1) * HBUF;
        unsigned short* hn = shH + ((t + 1) & 1) * HBUF;
        const unsigned short* brow = hb + bbase;

        // gate-r k=4..7 from global: issued at step start, consumed after
        // the LDS half (~460 cyc of MFMA slack — R6's proven timing)
        shortx8 gr0[4], gr1[4];
        #pragma unroll
        for (int kk = 0; kk < 4; ++kk) {
            gr0[kk] = *(const shortx8*)(gb0 + kk * 512);
            gr1[kk] = *(const shortx8*)(gb1 + kk * 512);
        }

        // n-gate hidden accumulators start from the b_hh bias constants
        acc[0][2] = nhb[0];
        acc[1][2] = nhb[1];

        // k=0..3: gate-r from LDS
        #pragma unroll
        for (int k = 0; k < 4; ++k) {
            shortx8 bf  = *(const shortx8*)(brow + k * 512);
            shortx8 ar0 = *(const shortx8*)(ab0 + k * 512);
            shortx8 ar1 = *(const shortx8*)(ab1 + k * 512);
            acc[0][0] = __builtin_amdgcn_mfma_f32_16x16x32_bf16(ar0,         bf, acc[0][0], 0, 0, 0);
            acc[1][0] = __builtin_amdgcn_mfma_f32_16x16x32_bf16(ar1,         bf, acc[1][0], 0, 0, 0);
            acc[0][1] = __builtin_amdgcn_mfma_f32_16x16x32_bf16(Wf[0][0][k], bf, acc[0][1], 0, 0, 0);
            acc[1][1] = __builtin_amdgcn_mfma_f32_16x16x32_bf16(Wf[1][0][k], bf, acc[1][1], 0, 0, 0);
            acc[0][2] = __builtin_amdgcn_mfma_f32_16x16x32_bf16(Wf[0][1][k], bf, acc[0][2], 0, 0, 0);
            acc[1][2] = __builtin_amdgcn_mfma_f32_16x16x32_bf16(Wf[1][1][k], bf, acc[1][2], 0, 0, 0);
        }
        // k=4..7: gate-r from the global prefetch
        #pragma unroll
        for (int k = 4; k < 8; ++k) {
            shortx8 bf = *(const shortx8*)(brow + k * 512);
            acc[0][0] = __builtin_amdgcn_mfma_f32_16x16x32_bf16(gr0[k - 4],  bf, acc[0][0], 0, 0, 0);
            acc[1][0] = __builtin_amdgcn_mfma_f32_16x16x32_bf16(gr1[k - 4],  bf, acc[1][0], 0, 0, 0);
            acc[0][1] = __builtin_amdgcn_mfma_f32_16x16x32_bf16(Wf[0][0][k], bf, acc[0][1], 0, 0, 0);
            acc[1][1] = __builtin_amdgcn_mfma_f32_16x16x32_bf16(Wf[1][0][k], bf, acc[1][1], 0, 0, 0);
            acc[0][2] = __builtin_amdgcn_mfma_f32_16x16x32_bf16(Wf[0][1][k], bf, acc[0][2], 0, 0, 0);
            acc[1][2] = __builtin_amdgcn_mfma_f32_16x16x32_bf16(Wf[1][1][k], bf, acc[1][2], 0, 0, 0);
        }

        // bx for step t+1 (read once; used per tile right after its epilogue)
#if HAVE_K16
        i16x4 bxn = *(const i16x4*)&shX[xidx];
#else
        ushortx4 xvn = *(const ushortx4*)&shX[xidx];
        shortx8 bxn = (q == 0)
            ? shortx8{(short)xvn[0], (short)xvn[1], (short)xvn[2], (short)xvn[3], 0, 0, 0, 0}
            : shortx8{0, 0, 0, 0, 0, 0, 0, 0};
#endif
        xidx += XT;

        // ---- interleaved tail: epilogue(tile) then its x-step re-init ----
        #pragma unroll
        for (int hti = 0; hti < 2; ++hti) {
            f32x4 hv = hold[hti];
            f32x4 ho;
            #pragma unroll
            for (int r = 0; r < 4; ++r) {
                float rr = sigmoid_(acc[hti][0][r]);
                float zz = sigmoid_(acc[hti][1][r]);
                float nn = tanh_(acc[hti][3][r] + rr * acc[hti][2][r]);
                ho[r] = nn + zz * (hv[r] - nn);
            }
            hold[hti] = ho;
            ushortx4 hb16 = {f2bf(ho[0]), f2bf(ho[1]), f2bf(ho[2]), f2bf(ho[3])};
            *(ushortx4*)(hn + woff[hti]) = hb16;
            if (IS_DEC) {
                *(ushortx4*)yp[hti] = hb16;
                yp[hti] += NBATCH * HID;   // stride 4096 shorts per step
            }
            // x-step re-init for t+1 (independent MFMAs under the trans tail)
#if HAVE_K16
            acc[hti][0] = MFMA_X(ax[hti][0], bxn, zc);
            acc[hti][1] = MFMA_X(ax[hti][1], bxn, zc);
            acc[hti][3] = MFMA_X(ax[hti][2], bxn, zc);
#else
            acc[hti][0] = __builtin_amdgcn_mfma_f32_16x16x32_bf16(ax[hti][0], bxn, zc, 0, 0, 0);
            acc[hti][1] = __builtin_amdgcn_mfma_f32_16x16x32_bf16(ax[hti][1], bxn, zc, 0, 0, 0);
            acc[hti][3] = __builtin_amdgcn_mfma_f32_16x16x32_bf16(ax[hti][2], bxn, zc, 0, 0, 0);
#endif
        }
        __syncthreads();
    }

    if (!IS_DEC) {
        // hand the decoder the EXACT fp32 final h
        #pragma unroll
        for (int hti = 0; hti < 2; ++hti) {
            int ht = w + hti * 8;
            int dim0 = ht * 16 + q * 4;
            *(f32x4*)(h_out + (size_t)(g * NBATCH + c) * HID + dim0) = hold[hti];
        }
    }
}

// out[b][t][d] = sum_h Y[g][t][b16][h] * W_fc[d][h] + b_fc[d]
__global__ __launch_bounds__(256) void proj_kernel(
    const unsigned short* __restrict__ Y, const float* __restrict__ W_fc,
    const float* __restrict__ b_fc, float* __restrict__ out)
{
    int row = blockIdx.x * 256 + threadIdx.x;  // ((g*T + t)*16 + b16)
    int b16 = row & 15;
    int gt = row >> 4;
    int t = gt & (T_LEN - 1);
    int g = gt >> 8;
    const unsigned short* y = Y + (size_t)row * HID;
    float a0 = b_fc[0], a1 = b_fc[1], a2 = b_fc[2];
    #pragma unroll 4
    for (int k8 = 0; k8 < 32; ++k8) {
        ushortx8 v = *(const ushortx8*)(y + k8 * 8);
        #pragma unroll
        for (int j = 0; j < 8; ++j) {
            float f = bf2f(v[j]);
            int k = k8 * 8 + j;
            a0 += f * W_fc[k];          // uniform -> scalar loads
            a1 += f * W_fc[256 + k];
            a2 += f * W_fc[512 + k];
        }
    }
    int batch = g * NBATCH + b16;
    float* o = out + ((size_t)batch * T_LEN + t) * 3;
    o[0] = a0; o[1] = a1; o[2] = a2;
}

extern "C" void kernel_launch(void* const* d_in, const int* in_sizes, int n_in,
                              void* d_out, int out_size, void* d_ws, size_t ws_size,
                              hipStream_t stream)
{
    const float* X_p      = (const float*)d_in[0];
    const float* X_f      = (const float*)d_in[1];
    const float* noise    = (const float*)d_in[2];
    const float* W_ih_enc = (const float*)d_in[3];
    const float* W_hh_enc = (const float*)d_in[4];
    const float* b_ih_enc = (const float*)d_in[5];
    const float* b_hh_enc = (const float*)d_in[6];
    const float* W_ih_dec = (const float*)d_in[7];
    const float* W_hh_dec = (const float*)d_in[8];
    const float* b_ih_dec = (const float*)d_in[9];
    const float* b_hh_dec = (const float*)d_in[10];
    const float* W_fc     = (const float*)d_in[11];
    const float* b_fc     = (const float*)d_in[12];

    // allow >64 KiB dynamic LDS (idempotent; host-side, graph-capture safe)
    (void)hipFuncSetAttribute((const void*)&gru_persistent<0>,
                              hipFuncAttributeMaxDynamicSharedMemorySize, SMEM_BYTES);
    (void)hipFuncSetAttribute((const void*)&gru_persistent<1>,
                              hipFuncAttributeMaxDynamicSharedMemorySize, SMEM_BYTES);

    // ws: [0,512K) h_enc fp32 | [512K,576K) Wr_enc | [576K,640K) Wr_dec |
    //     [640K, +67.1MB) decoder Y bf16
    float* h_enc = (float*)d_ws;
    unsigned short* wr_enc = (unsigned short*)((char*)d_ws + (512u << 10));
    unsigned short* wr_dec = (unsigned short*)((char*)d_ws + (576u << 10));
    unsigned short* Yws    = (unsigned short*)((char*)d_ws + (640u << 10));

    hipLaunchKernelGGL(prep_wr, dim3(32), dim3(256), 0, stream,
        W_hh_enc, W_hh_dec, wr_enc, wr_dec);

    hipLaunchKernelGGL((gru_persistent<0>), dim3(NBLK), dim3(NTHREADS), SMEM_BYTES, stream,
        X_p, W_hh_enc, W_ih_enc, b_ih_enc, b_hh_enc, wr_enc,
        (const float*)nullptr, (const float*)nullptr, h_enc,
        (unsigned short*)nullptr);

    hipLaunchKernelGGL((gru_persistent<1>), dim3(NBLK), dim3(NTHREADS), SMEM_BYTES, stream,
        X_f, W_hh_dec, W_ih_dec, b_ih_dec, b_hh_dec, wr_dec,
        h_enc, noise, (float*)nullptr, Yws);

    hipLaunchKernelGGL(proj_kernel, dim3((B_TOT * T_LEN) / 256), dim3(256), 0, stream,
        Yws, W_fc, b_fc, (float*)d_out);
}